// Round 2
// baseline (27269.153 us; speedup 1.0000x reference)
//
#include <hip/hip_runtime.h>
#include <math.h>

#define B_  1024
#define T_  512
#define D_  30
#define H1_ 96
#define G1_ 384
#define H2_ 64
#define G2_ 256

// Inter-kernel buffers as device globals (.bss, allocated at module load).
// Round-0 used d_ws for these; ws_size was the unverified assumption and the
// prime crash suspect (403 MB needed). Device globals remove the dependency.
// Both are fully overwritten every call before being read (no cross-call state).
__device__ float g_h1[(size_t)B_ * T_ * 192];   // 384 MiB: layer-1 output
__device__ float g_h2f[(size_t)B_ * H2_];       // layer-2 fwd final state

__device__ __forceinline__ float fast_tanh(float v) {
  float a = fabsf(v);
  float e = __expf(-2.0f * a);
  float t = 1.0f - 2.0f * e / (1.0f + e);
  return v < 0.0f ? -t : t;
}
__device__ __forceinline__ float fast_sigmoid(float v) {
  // sigma(x) = 0.5*(1+tanh(x/2)) -- exact identity, overflow-safe
  return 0.5f + 0.5f * fast_tanh(0.5f * v);
}

// ---------------------------------------------------------------------------
// Layer 1: bidirectional LSTM over x (B,T,30) -> g_h1 (B,T,192)
// grid (256, 2): blockIdx.x = batch tile of 4, blockIdx.y = dir (0 fwd, 1 bwd)
// block 384 threads: thread g owns gate g's 126 weights in VGPRs.
// ---------------------------------------------------------------------------
__global__ __launch_bounds__(384, 3)
void lstm1_kernel(const float* __restrict__ x,
                  const float* __restrict__ Wih_f, const float* __restrict__ Whh_f,
                  const float* __restrict__ bih_f, const float* __restrict__ bhh_f,
                  const float* __restrict__ Wih_b, const float* __restrict__ Whh_b,
                  const float* __restrict__ bih_b, const float* __restrict__ bhh_b)
{
  const int tid = threadIdx.x;
  const int dir = blockIdx.y;
  const int b0  = blockIdx.x * 4;

  const float* __restrict__ Wih = dir ? Wih_b : Wih_f;
  const float* __restrict__ Whh = dir ? Whh_b : Whh_f;
  const float* __restrict__ bih = dir ? bih_b : bih_f;
  const float* __restrict__ bhh = dir ? bhh_b : bhh_f;

  __shared__ __align__(16) float hx[4][128];   // [b][0:30 x | 32:128 h], pads zero
  __shared__ float gbuf[G1_ * 5];              // stride-5: 2-way bank alias (free)

  const int g = tid;                           // 384 threads == 384 gates
  float wreg[128];
  {
    const float* wr = Wih + g * D_;
#pragma unroll
    for (int k = 0; k < 32; ++k) wreg[k] = (k < D_) ? wr[k] : 0.0f;
    const float* hr = Whh + g * H1_;
#pragma unroll
    for (int k = 0; k < 96; ++k) wreg[32 + k] = hr[k];
  }
  const float bias = bih[g] + bhh[g];

  const int uj = tid % 96;                     // update pair (h unit, batch)
  const int ub = tid / 96;
  float c_state = 0.0f;

  for (int i = tid; i < 4 * 128; i += 384) (&hx[0][0])[i] = 0.0f;
  __syncthreads();
  const int xb = tid / 30;
  const int xd = tid - xb * 30;
  if (tid < 120) {
    const int t0 = dir ? (T_ - 1) : 0;
    hx[xb][xd] = x[((size_t)(b0 + xb) * T_ + t0) * D_ + xd];
  }
  __syncthreads();

  for (int s = 0; s < T_; ++s) {
    const int t = dir ? (T_ - 1 - s) : s;
    // prefetch next timestep's x into regs (latency hidden by gate compute)
    float xn = 0.0f;
    if (tid < 120 && s + 1 < T_) {
      const int tn = dir ? (t - 1) : (t + 1);
      xn = x[((size_t)(b0 + xb) * T_ + tn) * D_ + xd];
    }
    // gate GEMM: acc[b] = bias + W.x_t + U.h_{t-1}; broadcast b128 LDS reads
    float acc0 = bias, acc1 = bias, acc2 = bias, acc3 = bias;
    const float4* hx4 = (const float4*)(&hx[0][0]);
#pragma unroll
    for (int q = 0; q < 32; ++q) {
      float4 v0 = hx4[q];
      float4 v1 = hx4[32 + q];
      float4 v2 = hx4[64 + q];
      float4 v3 = hx4[96 + q];
      const float w0 = wreg[4*q+0], w1 = wreg[4*q+1], w2 = wreg[4*q+2], w3 = wreg[4*q+3];
      acc0 = fmaf(w0, v0.x, acc0); acc0 = fmaf(w1, v0.y, acc0); acc0 = fmaf(w2, v0.z, acc0); acc0 = fmaf(w3, v0.w, acc0);
      acc1 = fmaf(w0, v1.x, acc1); acc1 = fmaf(w1, v1.y, acc1); acc1 = fmaf(w2, v1.z, acc1); acc1 = fmaf(w3, v1.w, acc1);
      acc2 = fmaf(w0, v2.x, acc2); acc2 = fmaf(w1, v2.y, acc2); acc2 = fmaf(w2, v2.z, acc2); acc2 = fmaf(w3, v2.w, acc2);
      acc3 = fmaf(w0, v3.x, acc3); acc3 = fmaf(w1, v3.y, acc3); acc3 = fmaf(w2, v3.z, acc3); acc3 = fmaf(w3, v3.w, acc3);
    }
    gbuf[g*5+0] = acc0; gbuf[g*5+1] = acc1; gbuf[g*5+2] = acc2; gbuf[g*5+3] = acc3;
    __syncthreads();
    // x_{t+1} into LDS (gate reads of hx are done)
    if (tid < 120 && s + 1 < T_) hx[xb][xd] = xn;
    // elementwise LSTM cell update: one (j,b) pair per thread
    {
      float gi = gbuf[(uj      ) * 5 + ub];
      float gf = gbuf[(uj +  96) * 5 + ub];
      float gg = gbuf[(uj + 192) * 5 + ub];
      float go = gbuf[(uj + 288) * 5 + ub];
      float iv = fast_sigmoid(gi);
      float fv = fast_sigmoid(gf);
      float ov = fast_sigmoid(go);
      c_state = fv * c_state + iv * fast_tanh(gg);
      float h = ov * fast_tanh(c_state);
      hx[ub][32 + uj] = h;
      g_h1[((size_t)(b0 + ub) * T_ + t) * 192 + dir * 96 + uj] = h;
    }
    __syncthreads();
  }
}

// ---------------------------------------------------------------------------
// Layer 2 forward scan: g_h1 (B,T,192) -> g_h2f final state (B,64)
// grid 512: 2 batch/block. block 512 threads: (gate g, k-half) per thread,
// 128 weights in VGPRs each, partials combined through LDS.
// ---------------------------------------------------------------------------
__global__ __launch_bounds__(512, 3)
void lstm2f_kernel(const float* __restrict__ Wih, const float* __restrict__ Whh,
                   const float* __restrict__ bih, const float* __restrict__ bhh)
{
  const int tid  = threadIdx.x;
  const int b0   = blockIdx.x * 2;
  const int g    = tid & 255;
  const int half = tid >> 8;

  __shared__ __align__(16) float hx[2][256];   // [b][0:192 h1 | 192:256 h2prev]
  __shared__ float gbuf[G2_ * 5];

  float wreg[128];
  if (half == 0) {                             // k = 0..127 (h1 part)
    const float* wr = Wih + g * 192;
#pragma unroll
    for (int k = 0; k < 128; ++k) wreg[k] = wr[k];
  } else {                                     // k = 128..255 (h1 tail + h2)
    const float* wr = Wih + g * 192 + 128;
#pragma unroll
    for (int k = 0; k < 64; ++k) wreg[k] = wr[k];
    const float* hr = Whh + g * H2_;
#pragma unroll
    for (int k = 0; k < 64; ++k) wreg[64 + k] = hr[k];
  }
  const float bias = (half == 0) ? (bih[g] + bhh[g]) : 0.0f;

  const int uj = tid & 63;
  const int ub = (tid >> 6) & 1;
  float c_state = 0.0f;

  for (int i = tid; i < 2 * 256; i += 512) (&hx[0][0])[i] = 0.0f;
  __syncthreads();
  const int pb = tid / 96;
  const int pj = tid - pb * 96;
  if (tid < 192) {
    *(float2*)&hx[pb][pj * 2] =
        *(const float2*)&g_h1[((size_t)(b0 + pb) * T_ + 0) * 192 + pj * 2];
  }
  __syncthreads();

  const int qoff = half * 32;
  for (int s = 0; s < T_; ++s) {
    float2 pre = make_float2(0.0f, 0.0f);
    if (tid < 192 && s + 1 < T_) {
      pre = *(const float2*)&g_h1[((size_t)(b0 + pb) * T_ + (s + 1)) * 192 + pj * 2];
    }
    float acc0 = bias, acc1 = bias;
    const float4* hx4 = (const float4*)(&hx[0][0]);
#pragma unroll
    for (int q = 0; q < 32; ++q) {
      float4 v0 = hx4[qoff + q];
      float4 v1 = hx4[64 + qoff + q];
      const float w0 = wreg[4*q+0], w1 = wreg[4*q+1], w2 = wreg[4*q+2], w3 = wreg[4*q+3];
      acc0 = fmaf(w0, v0.x, acc0); acc0 = fmaf(w1, v0.y, acc0); acc0 = fmaf(w2, v0.z, acc0); acc0 = fmaf(w3, v0.w, acc0);
      acc1 = fmaf(w0, v1.x, acc1); acc1 = fmaf(w1, v1.y, acc1); acc1 = fmaf(w2, v1.z, acc1); acc1 = fmaf(w3, v1.w, acc1);
    }
    if (half == 1) { gbuf[g*5+0] = acc0; gbuf[g*5+1] = acc1; }
    __syncthreads();
    if (half == 0) { gbuf[g*5+0] += acc0; gbuf[g*5+1] += acc1; }
    __syncthreads();
    if (tid < 192 && s + 1 < T_) *(float2*)&hx[pb][pj * 2] = pre;
    if (tid < 128) {
      float gi = gbuf[(uj      ) * 5 + ub];
      float gf = gbuf[(uj +  64) * 5 + ub];
      float gg = gbuf[(uj + 128) * 5 + ub];
      float go = gbuf[(uj + 192) * 5 + ub];
      float iv = fast_sigmoid(gi), fv = fast_sigmoid(gf), ov = fast_sigmoid(go);
      c_state = fv * c_state + iv * fast_tanh(gg);
      float h = ov * fast_tanh(c_state);
      hx[ub][192 + uj] = h;
      if (s == T_ - 1) g_h2f[(b0 + ub) * H2_ + uj] = h;
    }
    __syncthreads();
  }
}

// ---------------------------------------------------------------------------
// Tail: layer-2 backward (ONE step: yb[T-1] = step from zero state on
// h1[:,T-1,:]) + dense head. grid 128 x 256 threads, 8 batch/block.
// ---------------------------------------------------------------------------
__global__ __launch_bounds__(256)
void tail_kernel(const float* __restrict__ Wih, const float* __restrict__ bih,
                 const float* __restrict__ bhh,
                 const float* __restrict__ W1, const float* __restrict__ b1,
                 const float* __restrict__ W2, const float* __restrict__ b2,
                 float* __restrict__ out)
{
  const int tid = threadIdx.x;
  const int b0  = blockIdx.x * 8;

  __shared__ __align__(16) float hl[8][192];    // h1 at t = T-1
  __shared__ float gb[G2_ * 9];                 // stride-9: 2-way alias only
  __shared__ __align__(16) float last[8][128];  // [h2f | h2b]
  __shared__ float db[8][32];

  for (int i = tid; i < 8 * 96; i += 256) {
    int bb = i / 96, jj = i - (i / 96) * 96;
    *(float2*)&hl[bb][jj * 2] =
        *(const float2*)&g_h1[((size_t)(b0 + bb) * T_ + (T_ - 1)) * 192 + jj * 2];
  }
  for (int i = tid; i < 8 * 64; i += 256) {
    int bb = i >> 6, jj = i & 63;
    last[bb][jj] = g_h2f[(b0 + bb) * H2_ + jj];
  }
  __syncthreads();

  // one LSTM step from zero state: gates for 8 batch elems, gate g = tid
  {
    const int gg_ = tid;
    const float* wr = Wih + gg_ * 192;
    const float bias = bih[gg_] + bhh[gg_];
    float acc[8];
#pragma unroll
    for (int b = 0; b < 8; ++b) acc[b] = bias;
#pragma unroll 4
    for (int q = 0; q < 48; ++q) {
      float4 wv = *(const float4*)&wr[q * 4];
#pragma unroll
      for (int b = 0; b < 8; ++b) {
        float4 v = *(const float4*)&hl[b][q * 4];
        acc[b] = fmaf(wv.x, v.x, acc[b]);
        acc[b] = fmaf(wv.y, v.y, acc[b]);
        acc[b] = fmaf(wv.z, v.z, acc[b]);
        acc[b] = fmaf(wv.w, v.w, acc[b]);
      }
    }
#pragma unroll
    for (int b = 0; b < 8; ++b) gb[gg_ * 9 + b] = acc[b];
  }
  __syncthreads();

  for (int p = tid; p < 512; p += 256) {
    int jj = p & 63, bb = p >> 6;
    float gi = gb[(jj      ) * 9 + bb];
    float gg = gb[(jj + 128) * 9 + bb];
    float go = gb[(jj + 192) * 9 + bb];
    float c  = fast_sigmoid(gi) * fast_tanh(gg);   // c_prev = 0 (f gate moot)
    float h  = fast_sigmoid(go) * fast_tanh(c);
    last[bb][64 + jj] = h;
  }
  __syncthreads();

  // dense1 + relu: (B,128) -> (B,32)
  {
    int u = tid & 31, bb = tid >> 5;
    const float* wr1 = W1 + u * 128;
    float a = b1[u];
#pragma unroll
    for (int q = 0; q < 32; ++q) {
      float4 wv = *(const float4*)&wr1[q * 4];
      float4 v  = *(const float4*)&last[bb][q * 4];
      a = fmaf(wv.x, v.x, a); a = fmaf(wv.y, v.y, a);
      a = fmaf(wv.z, v.z, a); a = fmaf(wv.w, v.w, a);
    }
    db[bb][u] = fmaxf(a, 0.0f);
  }
  __syncthreads();

  if (tid < 8) {
    float a = b2[0];
#pragma unroll
    for (int u2 = 0; u2 < 32; ++u2) a = fmaf(db[tid][u2], W2[u2], a);
    out[b0 + tid] = a;
  }
}

extern "C" void kernel_launch(void* const* d_in, const int* in_sizes, int n_in,
                              void* d_out, int out_size, void* d_ws, size_t ws_size,
                              hipStream_t stream)
{
  const float* x     = (const float*)d_in[0];
  const float* Wih1f = (const float*)d_in[1];
  const float* Whh1f = (const float*)d_in[2];
  const float* bih1f = (const float*)d_in[3];
  const float* bhh1f = (const float*)d_in[4];
  const float* Wih1b = (const float*)d_in[5];
  const float* Whh1b = (const float*)d_in[6];
  const float* bih1b = (const float*)d_in[7];
  const float* bhh1b = (const float*)d_in[8];
  const float* Wih2f = (const float*)d_in[9];
  const float* Whh2f = (const float*)d_in[10];
  const float* bih2f = (const float*)d_in[11];
  const float* bhh2f = (const float*)d_in[12];
  const float* Wih2b = (const float*)d_in[13];
  /* Whh2b (d_in[14]) unused: layer-2 backward at t=T-1 is one step from h=0 */
  const float* bih2b = (const float*)d_in[15];
  const float* bhh2b = (const float*)d_in[16];
  const float* W1    = (const float*)d_in[17];
  const float* b1    = (const float*)d_in[18];
  const float* W2    = (const float*)d_in[19];
  const float* b2    = (const float*)d_in[20];

  (void)d_ws; (void)ws_size; (void)in_sizes; (void)n_in; (void)out_size;

  lstm1_kernel<<<dim3(256, 2), 384, 0, stream>>>(
      x, Wih1f, Whh1f, bih1f, bhh1f, Wih1b, Whh1b, bih1b, bhh1b);
  lstm2f_kernel<<<512, 512, 0, stream>>>(
      Wih2f, Whh2f, bih2f, bhh2f);
  tail_kernel<<<128, 256, 0, stream>>>(
      Wih2b, bih2b, bhh2b, W1, b1, W2, b2, (float*)d_out);
}

// Round 3
// 3485.003 us; speedup vs baseline: 7.8247x; 7.8247x over previous
//
#include <hip/hip_runtime.h>
#include <math.h>

#define B_  1024
#define T_  512
#define D_  30
#define H1_ 96
#define G1_ 384
#define H2_ 64
#define G2_ 256

// Inter-kernel buffers as device globals (.bss, bound at module load).
// Fully overwritten every call before being read (no cross-call state).
__device__ float g_h1[(size_t)B_ * T_ * 192];   // 384 MiB: layer-1 output
__device__ float g_h2f[(size_t)B_ * H2_];       // layer-2 fwd final state

__device__ __forceinline__ float fast_tanh(float v) {
  float a = fabsf(v);
  float e = __expf(-2.0f * a);
  float t = 1.0f - 2.0f * e / (1.0f + e);
  return v < 0.0f ? -t : t;
}
__device__ __forceinline__ float fast_sigmoid(float v) {
  return 0.5f + 0.5f * fast_tanh(0.5f * v);   // exact identity, overflow-safe
}

#define REP16(M) M(0) M(1) M(2) M(3) M(4) M(5) M(6) M(7) \
                 M(8) M(9) M(10) M(11) M(12) M(13) M(14) M(15)

// ---------------------------------------------------------------------------
// Layer 1: bidirectional LSTM over x (B,T,30) -> g_h1 (B,T,192)
// grid (128, 2): blockIdx.x = batch tile of 8, blockIdx.y = dir.
// 768 threads: (gate g = tid%384, k-half = tid/384). 64 weights per thread in
// 16 NAMED float4 regs (SSA values -- cannot be demoted to scratch; the
// round-2 float[128] array spilled: VGPR_Count=84, 31 GB scratch FETCH).
// Unified input vec v[128]: [0:30)=x_t, [30:32)=0, [32:128)=h_{t-1}.
// ---------------------------------------------------------------------------
__global__ __launch_bounds__(768, 3)
void lstm1_kernel(const float* __restrict__ x,
                  const float* __restrict__ Wih_f, const float* __restrict__ Whh_f,
                  const float* __restrict__ bih_f, const float* __restrict__ bhh_f,
                  const float* __restrict__ Wih_b, const float* __restrict__ Whh_b,
                  const float* __restrict__ bih_b, const float* __restrict__ bhh_b)
{
  const int tid = threadIdx.x;
  const int dir = blockIdx.y;
  const int b0  = blockIdx.x * 8;

  const float* __restrict__ Wih = dir ? Wih_b : Wih_f;
  const float* __restrict__ Whh = dir ? Whh_b : Whh_f;
  const float* __restrict__ bih = dir ? bih_b : bih_f;
  const float* __restrict__ bhh = dir ? bhh_b : bhh_f;

  __shared__ __align__(16) float hx[8][128];     // [b][0:30 x | 32:128 h]
  __shared__ float gbuf[G1_ * 17];               // [g][b*2+half], stride 17: conflict-free

  const int g    = tid % 384;                    // wave-uniform half (384 = 6*64)
  const int half = tid / 384;

  float4 w0,w1,w2,w3,w4,w5,w6,w7,w8,w9,w10,w11,w12,w13,w14,w15;
  if (half == 0) {                               // k = 0..63: x-part + h[0:32)
    const float* wr = Wih + g * D_;
    w0 = make_float4(wr[ 0], wr[ 1], wr[ 2], wr[ 3]);
    w1 = make_float4(wr[ 4], wr[ 5], wr[ 6], wr[ 7]);
    w2 = make_float4(wr[ 8], wr[ 9], wr[10], wr[11]);
    w3 = make_float4(wr[12], wr[13], wr[14], wr[15]);
    w4 = make_float4(wr[16], wr[17], wr[18], wr[19]);
    w5 = make_float4(wr[20], wr[21], wr[22], wr[23]);
    w6 = make_float4(wr[24], wr[25], wr[26], wr[27]);
    w7 = make_float4(wr[28], wr[29], 0.0f, 0.0f);
    const float4* hq = (const float4*)(Whh + g * H1_);      // 16B-aligned (g*384 B)
    w8 = hq[0]; w9 = hq[1]; w10 = hq[2]; w11 = hq[3];
    w12 = hq[4]; w13 = hq[5]; w14 = hq[6]; w15 = hq[7];
  } else {                                       // k = 64..127: h[32:96)
    const float4* hq = (const float4*)(Whh + g * H1_ + 32);
    w0 = hq[0];  w1 = hq[1];  w2 = hq[2];  w3 = hq[3];
    w4 = hq[4];  w5 = hq[5];  w6 = hq[6];  w7 = hq[7];
    w8 = hq[8];  w9 = hq[9];  w10 = hq[10]; w11 = hq[11];
    w12 = hq[12]; w13 = hq[13]; w14 = hq[14]; w15 = hq[15];
  }

  // every thread is also a cell-updater: unit uj, batch ub (96*8 = 768)
  const int uj = tid % 96;
  const int ub = tid / 96;
  const float bias_i = bih[uj      ] + bhh[uj      ];
  const float bias_f = bih[uj +  96] + bhh[uj +  96];
  const float bias_g = bih[uj + 192] + bhh[uj + 192];
  const float bias_o = bih[uj + 288] + bhh[uj + 288];
  float c_state = 0.0f;

  for (int i = tid; i < 8 * 128; i += 768) (&hx[0][0])[i] = 0.0f;
  __syncthreads();
  const int xb = tid / 30;
  const int xd = tid - xb * 30;
  if (tid < 240) {
    const int t0 = dir ? (T_ - 1) : 0;
    hx[xb][xd] = x[((size_t)(b0 + xb) * T_ + t0) * D_ + xd];
  }
  __syncthreads();

  const int qoff = half * 16;
  const float4* hx4 = (const float4*)(&hx[0][0]);

  for (int s = 0; s < T_; ++s) {
    const int t = dir ? (T_ - 1 - s) : s;
    float xn = 0.0f;
    if (tid < 240 && s + 1 < T_) {
      const int tn = dir ? (t - 1) : (t + 1);
      xn = x[((size_t)(b0 + xb) * T_ + tn) * D_ + xd];
    }
    float acc0 = 0.f, acc1 = 0.f, acc2 = 0.f, acc3 = 0.f;
    float acc4 = 0.f, acc5 = 0.f, acc6 = 0.f, acc7 = 0.f;
#define FB1(i) {                                                              \
    float4 v0 = hx4[0*32 + qoff + i]; float4 v1 = hx4[1*32 + qoff + i];       \
    float4 v2 = hx4[2*32 + qoff + i]; float4 v3 = hx4[3*32 + qoff + i];       \
    float4 v4 = hx4[4*32 + qoff + i]; float4 v5 = hx4[5*32 + qoff + i];       \
    float4 v6 = hx4[6*32 + qoff + i]; float4 v7 = hx4[7*32 + qoff + i];       \
    acc0 = fmaf(w##i.x, v0.x, acc0); acc0 = fmaf(w##i.y, v0.y, acc0);         \
    acc0 = fmaf(w##i.z, v0.z, acc0); acc0 = fmaf(w##i.w, v0.w, acc0);         \
    acc1 = fmaf(w##i.x, v1.x, acc1); acc1 = fmaf(w##i.y, v1.y, acc1);         \
    acc1 = fmaf(w##i.z, v1.z, acc1); acc1 = fmaf(w##i.w, v1.w, acc1);         \
    acc2 = fmaf(w##i.x, v2.x, acc2); acc2 = fmaf(w##i.y, v2.y, acc2);         \
    acc2 = fmaf(w##i.z, v2.z, acc2); acc2 = fmaf(w##i.w, v2.w, acc2);         \
    acc3 = fmaf(w##i.x, v3.x, acc3); acc3 = fmaf(w##i.y, v3.y, acc3);         \
    acc3 = fmaf(w##i.z, v3.z, acc3); acc3 = fmaf(w##i.w, v3.w, acc3);         \
    acc4 = fmaf(w##i.x, v4.x, acc4); acc4 = fmaf(w##i.y, v4.y, acc4);         \
    acc4 = fmaf(w##i.z, v4.z, acc4); acc4 = fmaf(w##i.w, v4.w, acc4);         \
    acc5 = fmaf(w##i.x, v5.x, acc5); acc5 = fmaf(w##i.y, v5.y, acc5);         \
    acc5 = fmaf(w##i.z, v5.z, acc5); acc5 = fmaf(w##i.w, v5.w, acc5);         \
    acc6 = fmaf(w##i.x, v6.x, acc6); acc6 = fmaf(w##i.y, v6.y, acc6);         \
    acc6 = fmaf(w##i.z, v6.z, acc6); acc6 = fmaf(w##i.w, v6.w, acc6);         \
    acc7 = fmaf(w##i.x, v7.x, acc7); acc7 = fmaf(w##i.y, v7.y, acc7);         \
    acc7 = fmaf(w##i.z, v7.z, acc7); acc7 = fmaf(w##i.w, v7.w, acc7); }
    REP16(FB1)
#undef FB1
    {
      const int gb = g * 17 + half;              // lanes: g consecutive, stride 17
      gbuf[gb +  0] = acc0; gbuf[gb +  2] = acc1;
      gbuf[gb +  4] = acc2; gbuf[gb +  6] = acc3;
      gbuf[gb +  8] = acc4; gbuf[gb + 10] = acc5;
      gbuf[gb + 12] = acc6; gbuf[gb + 14] = acc7;
    }
    __syncthreads();
    if (tid < 240 && s + 1 < T_) hx[xb][xd] = xn;
    {
      const int ro = ub * 2;
      float gi = gbuf[(uj      ) * 17 + ro] + gbuf[(uj      ) * 17 + ro + 1] + bias_i;
      float gf = gbuf[(uj +  96) * 17 + ro] + gbuf[(uj +  96) * 17 + ro + 1] + bias_f;
      float gg = gbuf[(uj + 192) * 17 + ro] + gbuf[(uj + 192) * 17 + ro + 1] + bias_g;
      float go = gbuf[(uj + 288) * 17 + ro] + gbuf[(uj + 288) * 17 + ro + 1] + bias_o;
      float iv = fast_sigmoid(gi);
      float fv = fast_sigmoid(gf);
      float ov = fast_sigmoid(go);
      c_state = fv * c_state + iv * fast_tanh(gg);
      float h = ov * fast_tanh(c_state);
      hx[ub][32 + uj] = h;
      g_h1[((size_t)(b0 + ub) * T_ + t) * 192 + dir * 96 + uj] = h;
    }
    __syncthreads();
  }
}

// ---------------------------------------------------------------------------
// Layer 2 forward scan: g_h1 (B,T,192) -> g_h2f (B,64).
// grid 256: 4 batch/block. 1024 threads: (gate g = tid&255, k-quarter =
// tid>>8). 64 weights per thread in named float4 regs. v[256]: [0:192)=h1_t,
// [192:256)=h2_{t-1}.
// ---------------------------------------------------------------------------
__global__ __launch_bounds__(1024, 4)
void lstm2f_kernel(const float* __restrict__ Wih, const float* __restrict__ Whh,
                   const float* __restrict__ bih, const float* __restrict__ bhh)
{
  const int tid = threadIdx.x;
  const int b0  = blockIdx.x * 4;
  const int g   = tid & 255;
  const int q   = tid >> 8;                      // wave-uniform (256 = 4 waves)

  __shared__ __align__(16) float hx[4][256];     // [b][0:192 h1 | 192:256 h2prev]
  __shared__ float gbuf[G2_ * 17];               // [g][b*4+q], stride 17

  float4 w0,w1,w2,w3,w4,w5,w6,w7,w8,w9,w10,w11,w12,w13,w14,w15;
  {
    const float4* wq = (q < 3) ? (const float4*)(Wih + g * 192 + 64 * q)
                               : (const float4*)(Whh + g * H2_);
    w0 = wq[0];  w1 = wq[1];  w2 = wq[2];  w3 = wq[3];
    w4 = wq[4];  w5 = wq[5];  w6 = wq[6];  w7 = wq[7];
    w8 = wq[8];  w9 = wq[9];  w10 = wq[10]; w11 = wq[11];
    w12 = wq[12]; w13 = wq[13]; w14 = wq[14]; w15 = wq[15];
  }

  const int uj = tid & 63;                       // updaters: tid < 256
  const int ub = (tid >> 6) & 3;
  const float bias_i = bih[uj      ] + bhh[uj      ];
  const float bias_f = bih[uj +  64] + bhh[uj +  64];
  const float bias_g = bih[uj + 128] + bhh[uj + 128];
  const float bias_o = bih[uj + 192] + bhh[uj + 192];
  float c_state = 0.0f;

  for (int i = tid; i < 4 * 256; i += 1024) (&hx[0][0])[i] = 0.0f;
  __syncthreads();
  const int pb = tid / 96;                       // h1 stagers: tid < 384
  const int pj = tid - pb * 96;
  if (tid < 384) {
    *(float2*)&hx[pb][pj * 2] =
        *(const float2*)&g_h1[((size_t)(b0 + pb) * T_ + 0) * 192 + pj * 2];
  }
  __syncthreads();

  const int qoff = q * 16;
  const float4* hx4 = (const float4*)(&hx[0][0]);

  for (int s = 0; s < T_; ++s) {
    float2 pre = make_float2(0.0f, 0.0f);
    if (tid < 384 && s + 1 < T_) {
      pre = *(const float2*)&g_h1[((size_t)(b0 + pb) * T_ + (s + 1)) * 192 + pj * 2];
    }
    float acc0 = 0.f, acc1 = 0.f, acc2 = 0.f, acc3 = 0.f;
#define FB2(i) {                                                              \
    float4 v0 = hx4[0*64 + qoff + i]; float4 v1 = hx4[1*64 + qoff + i];       \
    float4 v2 = hx4[2*64 + qoff + i]; float4 v3 = hx4[3*64 + qoff + i];       \
    acc0 = fmaf(w##i.x, v0.x, acc0); acc0 = fmaf(w##i.y, v0.y, acc0);         \
    acc0 = fmaf(w##i.z, v0.z, acc0); acc0 = fmaf(w##i.w, v0.w, acc0);         \
    acc1 = fmaf(w##i.x, v1.x, acc1); acc1 = fmaf(w##i.y, v1.y, acc1);         \
    acc1 = fmaf(w##i.z, v1.z, acc1); acc1 = fmaf(w##i.w, v1.w, acc1);         \
    acc2 = fmaf(w##i.x, v2.x, acc2); acc2 = fmaf(w##i.y, v2.y, acc2);         \
    acc2 = fmaf(w##i.z, v2.z, acc2); acc2 = fmaf(w##i.w, v2.w, acc2);         \
    acc3 = fmaf(w##i.x, v3.x, acc3); acc3 = fmaf(w##i.y, v3.y, acc3);         \
    acc3 = fmaf(w##i.z, v3.z, acc3); acc3 = fmaf(w##i.w, v3.w, acc3); }
    REP16(FB2)
#undef FB2
    {
      const int gb = g * 17 + q;                 // lanes: g consecutive, stride 17
      gbuf[gb +  0] = acc0; gbuf[gb +  4] = acc1;
      gbuf[gb +  8] = acc2; gbuf[gb + 12] = acc3;
    }
    __syncthreads();
    if (tid < 384 && s + 1 < T_) *(float2*)&hx[pb][pj * 2] = pre;
    if (tid < 256) {
      const int ro = ub * 4;
      float gi = bias_i, gf = bias_f, gg = bias_g, go = bias_o;
#pragma unroll
      for (int qq = 0; qq < 4; ++qq) {
        gi += gbuf[(uj      ) * 17 + ro + qq];
        gf += gbuf[(uj +  64) * 17 + ro + qq];
        gg += gbuf[(uj + 128) * 17 + ro + qq];
        go += gbuf[(uj + 192) * 17 + ro + qq];
      }
      float iv = fast_sigmoid(gi), fv = fast_sigmoid(gf), ov = fast_sigmoid(go);
      c_state = fv * c_state + iv * fast_tanh(gg);
      float h = ov * fast_tanh(c_state);
      hx[ub][192 + uj] = h;
      if (s == T_ - 1) g_h2f[(b0 + ub) * H2_ + uj] = h;
    }
    __syncthreads();
  }
}

// ---------------------------------------------------------------------------
// Tail: layer-2 backward (ONE step from zero state on h1[:,T-1,:]) + dense
// head. grid 128 x 256 threads, 8 batch/block. (negligible runtime)
// ---------------------------------------------------------------------------
__global__ __launch_bounds__(256)
void tail_kernel(const float* __restrict__ Wih, const float* __restrict__ bih,
                 const float* __restrict__ bhh,
                 const float* __restrict__ W1, const float* __restrict__ b1,
                 const float* __restrict__ W2, const float* __restrict__ b2,
                 float* __restrict__ out)
{
  const int tid = threadIdx.x;
  const int b0  = blockIdx.x * 8;

  __shared__ __align__(16) float hl[8][192];    // h1 at t = T-1
  __shared__ float gb[G2_ * 9];
  __shared__ __align__(16) float last[8][128];  // [h2f | h2b]
  __shared__ float db[8][32];

  for (int i = tid; i < 8 * 96; i += 256) {
    int bb = i / 96, jj = i - (i / 96) * 96;
    *(float2*)&hl[bb][jj * 2] =
        *(const float2*)&g_h1[((size_t)(b0 + bb) * T_ + (T_ - 1)) * 192 + jj * 2];
  }
  for (int i = tid; i < 8 * 64; i += 256) {
    int bb = i >> 6, jj = i & 63;
    last[bb][jj] = g_h2f[(b0 + bb) * H2_ + jj];
  }
  __syncthreads();

  {
    const int gg_ = tid;
    const float* wr = Wih + gg_ * 192;
    const float bias = bih[gg_] + bhh[gg_];
    float acc[8];
#pragma unroll
    for (int b = 0; b < 8; ++b) acc[b] = bias;
#pragma unroll 4
    for (int qq = 0; qq < 48; ++qq) {
      float4 wv = *(const float4*)&wr[qq * 4];
#pragma unroll
      for (int b = 0; b < 8; ++b) {
        float4 v = *(const float4*)&hl[b][qq * 4];
        acc[b] = fmaf(wv.x, v.x, acc[b]);
        acc[b] = fmaf(wv.y, v.y, acc[b]);
        acc[b] = fmaf(wv.z, v.z, acc[b]);
        acc[b] = fmaf(wv.w, v.w, acc[b]);
      }
    }
#pragma unroll
    for (int b = 0; b < 8; ++b) gb[gg_ * 9 + b] = acc[b];
  }
  __syncthreads();

  for (int p = tid; p < 512; p += 256) {
    int jj = p & 63, bb = p >> 6;
    float gi = gb[(jj      ) * 9 + bb];
    float gg = gb[(jj + 128) * 9 + bb];
    float go = gb[(jj + 192) * 9 + bb];
    float c  = fast_sigmoid(gi) * fast_tanh(gg);
    float h  = fast_sigmoid(go) * fast_tanh(c);
    last[bb][64 + jj] = h;
  }
  __syncthreads();

  {
    int u = tid & 31, bb = tid >> 5;
    const float* wr1 = W1 + u * 128;
    float a = b1[u];
#pragma unroll
    for (int qq = 0; qq < 32; ++qq) {
      float4 wv = *(const float4*)&wr1[qq * 4];
      float4 v  = *(const float4*)&last[bb][qq * 4];
      a = fmaf(wv.x, v.x, a); a = fmaf(wv.y, v.y, a);
      a = fmaf(wv.z, v.z, a); a = fmaf(wv.w, v.w, a);
    }
    db[bb][u] = fmaxf(a, 0.0f);
  }
  __syncthreads();

  if (tid < 8) {
    float a = b2[0];
#pragma unroll
    for (int u2 = 0; u2 < 32; ++u2) a = fmaf(db[tid][u2], W2[u2], a);
    out[b0 + tid] = a;
  }
}

extern "C" void kernel_launch(void* const* d_in, const int* in_sizes, int n_in,
                              void* d_out, int out_size, void* d_ws, size_t ws_size,
                              hipStream_t stream)
{
  const float* x     = (const float*)d_in[0];
  const float* Wih1f = (const float*)d_in[1];
  const float* Whh1f = (const float*)d_in[2];
  const float* bih1f = (const float*)d_in[3];
  const float* bhh1f = (const float*)d_in[4];
  const float* Wih1b = (const float*)d_in[5];
  const float* Whh1b = (const float*)d_in[6];
  const float* bih1b = (const float*)d_in[7];
  const float* bhh1b = (const float*)d_in[8];
  const float* Wih2f = (const float*)d_in[9];
  const float* Whh2f = (const float*)d_in[10];
  const float* bih2f = (const float*)d_in[11];
  const float* bhh2f = (const float*)d_in[12];
  const float* Wih2b = (const float*)d_in[13];
  /* Whh2b (d_in[14]) unused: layer-2 backward at t=T-1 is one step from h=0 */
  const float* bih2b = (const float*)d_in[15];
  const float* bhh2b = (const float*)d_in[16];
  const float* W1    = (const float*)d_in[17];
  const float* b1    = (const float*)d_in[18];
  const float* W2    = (const float*)d_in[19];
  const float* b2    = (const float*)d_in[20];

  (void)d_ws; (void)ws_size; (void)in_sizes; (void)n_in; (void)out_size;

  lstm1_kernel<<<dim3(128, 2), 768, 0, stream>>>(
      x, Wih1f, Whh1f, bih1f, bhh1f, Wih1b, Whh1b, bih1b, bhh1b);
  lstm2f_kernel<<<256, 1024, 0, stream>>>(
      Wih2f, Whh2f, bih2f, bhh2f);
  tail_kernel<<<128, 256, 0, stream>>>(
      Wih2b, bih2b, bhh2b, W1, b1, W2, b2, (float*)d_out);
}